// Round 2
// baseline (1786.621 us; speedup 1.0000x reference)
//
#include <hip/hip_runtime.h>
#include <stdint.h>

typedef unsigned long long u64;

// Problem constants
#define NROWS 16384   // B*H*W = 16*32*32
#define CDIM  256
#define NEMB  8192

// d_out layout (float offsets): z | z_q | indices | one_hot
#define Z_OFF   0ull
#define ZQ_OFF  4194304ull
#define IDX_OFF 8388608ull
#define OH_OFF  8404992ull

// ws layout: es[8192] f32 @ 0, zs[16384] f32 @ 32768 bytes. Total 96KB.
#define ES_OFF_BYTES 0
#define ZS_OFF_BYTES 32768

// order-preserving f32 -> u32 map (monotone increasing)
__device__ __forceinline__ unsigned fmap(float x) {
    unsigned u = __float_as_uint(x);
    return (u & 0x80000000u) ? ~u : (u | 0x80000000u);
}

// ---------------------------------------------------------------------------
// Kernel A: transpose z_e [B,C,H,W] -> z [B,H,W,C] (output 0; also GEMM A)
// ---------------------------------------------------------------------------
__global__ __launch_bounds__(256) void k_transpose(const float* __restrict__ ze,
                                                   float* __restrict__ z) {
    __shared__ float T[64][65];
    int b = blockIdx.z;          // 0..15
    int ct = blockIdx.x;         // 0..3   (c tiles of 64)
    int ht = blockIdx.y;         // 0..15  (hw tiles of 64)
    int c0 = ct * 64, hw0 = ht * 64;
    int lane = threadIdx.x & 63;
    int grp  = threadIdx.x >> 6; // 0..3
    #pragma unroll
    for (int i = 0; i < 16; ++i) {
        int cl = grp + i * 4;
        T[cl][lane] = ze[((size_t)(b * 256 + c0 + cl)) * 1024 + hw0 + lane];
    }
    __syncthreads();
    #pragma unroll
    for (int i = 0; i < 16; ++i) {
        int hwl = grp + i * 4;
        z[((size_t)(b * 1024 + hw0 + hwl)) * 256 + c0 + lane] = T[lane][hwl];
    }
}

// ---------------------------------------------------------------------------
// numpy pairwise_sum emulation (bit-exact), n=256 = pw128(x) + pw128(x+128).
// pw128: 8 accumulators, r[j] += fl(x[i+j]^2), combine ((r0+r1)+(r2+r3))+((r4+r5)+(r6+r7)).
// __f*_rn intrinsics forbid FMA contraction (np squares elementwise, THEN adds).
// ---------------------------------------------------------------------------
__device__ __forceinline__ float pw128sq(const float* __restrict__ x) {
    float r[8];
    #pragma unroll
    for (int j = 0; j < 8; ++j) r[j] = __fmul_rn(x[j], x[j]);
    #pragma unroll
    for (int i = 8; i < 128; i += 8) {
        #pragma unroll
        for (int j = 0; j < 8; ++j)
            r[j] = __fadd_rn(r[j], __fmul_rn(x[i + j], x[i + j]));
    }
    return __fadd_rn(__fadd_rn(__fadd_rn(r[0], r[1]), __fadd_rn(r[2], r[3])),
                     __fadd_rn(__fadd_rn(r[4], r[5]), __fadd_rn(r[6], r[7])));
}

// one thread per row; rows of 256 f32. L1 holds the wave's 64 active lines.
__global__ __launch_bounds__(256) void k_rowsq(const float* __restrict__ X,
                                               float* __restrict__ out,
                                               int nrows) {
    int r = blockIdx.x * 256 + threadIdx.x;
    if (r >= nrows) return;
    const float* x = &X[(size_t)r * 256];
    out[r] = __fadd_rn(pw128sq(x), pw128sq(x + 128));
}

// ---------------------------------------------------------------------------
// Kernel C: distance GEMM (f32 VALU, sequential-k FMA chain == BLAS microkernel),
// epilogue computes np-f32-emulated d = fl(fl(zs+es) - fl(2*dot)) and reduces
// the (d,k) min-key per (row, 128-col chunk) into the one_hot region
// (row's first 64 u64 slots — zeroed later by k_final).
// ---------------------------------------------------------------------------
#define BM 128
#define BN 128
#define BK 32
#define LDA 129

__global__ __launch_bounds__(256) void k_dist(const float* __restrict__ Z,
                                              const float* __restrict__ E,
                                              const float* __restrict__ es,
                                              const float* __restrict__ zs,
                                              float* __restrict__ oh) {
    __shared__ __align__(16) char smem[33024];  // As/Bs then u64 red[128][17]
    float* As = (float*)smem;
    float* Bs = As + BK * LDA;
    u64*   red = (u64*)smem;

    int bx = blockIdx.x;   // col tile 0..63
    int by = blockIdx.y;   // row tile 0..127
    int tid = threadIdx.x;
    int tx = tid & 15, ty = tid >> 4;
    int row0 = by * BM, col0 = bx * BN;

    float acc[8][8] = {};

    for (int kk = 0; kk < CDIM; kk += BK) {
        #pragma unroll
        for (int it = 0; it < 4; ++it) {
            int f4 = tid + it * 256;   // 0..1023
            int r = f4 >> 3, q = f4 & 7;
            float4 va = *(const float4*)&Z[((size_t)(row0 + r)) * CDIM + kk + q * 4];
            As[(q * 4 + 0) * LDA + r] = va.x;
            As[(q * 4 + 1) * LDA + r] = va.y;
            As[(q * 4 + 2) * LDA + r] = va.z;
            As[(q * 4 + 3) * LDA + r] = va.w;
            float4 vb = *(const float4*)&E[((size_t)(col0 + r)) * CDIM + kk + q * 4];
            Bs[(q * 4 + 0) * LDA + r] = vb.x;
            Bs[(q * 4 + 1) * LDA + r] = vb.y;
            Bs[(q * 4 + 2) * LDA + r] = vb.z;
            Bs[(q * 4 + 3) * LDA + r] = vb.w;
        }
        __syncthreads();
        for (int k = 0; k < BK; ++k) {
            float a[8], b[8];
            #pragma unroll
            for (int i = 0; i < 8; ++i) a[i] = As[k * LDA + ty * 8 + i];
            #pragma unroll
            for (int j = 0; j < 8; ++j) b[j] = Bs[k * LDA + tx * 8 + j];
            #pragma unroll
            for (int i = 0; i < 8; ++i)
                #pragma unroll
                for (int j = 0; j < 8; ++j)
                    acc[i][j] = fmaf(a[i], b[j], acc[i][j]);
        }
        __syncthreads();
    }

    // epilogue: np-f32 emulation. d = fl(fl(zs_row + es_col) - fl(2*dot)).
    float esj[8], zsi[8];
    #pragma unroll
    for (int j = 0; j < 8; ++j) esj[j] = es[col0 + tx * 8 + j];
    #pragma unroll
    for (int i = 0; i < 8; ++i) zsi[i] = zs[row0 + ty * 8 + i];

    #pragma unroll
    for (int i = 0; i < 8; ++i) {
        u64 best = ~0ull;
        #pragma unroll
        for (int j = 0; j < 8; ++j) {
            float t1 = __fadd_rn(zsi[i], esj[j]);
            float t2 = __fmul_rn(2.0f, acc[i][j]);
            float d  = __fsub_rn(t1, t2);
            u64 key = ((u64)fmap(d) << 32) | (unsigned)(col0 + tx * 8 + j);
            if (key < best) best = key;
        }
        red[(ty * 8 + i) * 17 + tx] = best;
    }
    __syncthreads();
    if (tid < 128) {
        u64 best = ~0ull;
        #pragma unroll
        for (int s = 0; s < 16; ++s) {
            u64 k = red[tid * 17 + s];
            if (k < best) best = k;
        }
        // stash in this row's one_hot slice (u64 slot bx of first 512 bytes)
        u64* krow = (u64*)(oh + ((size_t)(row0 + tid)) * NEMB);
        krow[bx] = best;
    }
}

// ---------------------------------------------------------------------------
// Kernel D: per-row finalize — min over 64 chunk keys (np first-min tie-break),
// zero the one_hot row (erasing the stashed keys), write 1.0 / z_q / index.
// ---------------------------------------------------------------------------
__global__ __launch_bounds__(256) void k_final(const float* __restrict__ E,
                                               float* __restrict__ zq,
                                               float* __restrict__ idxf,
                                               float* __restrict__ oh) {
    __shared__ u64 kl[64];
    __shared__ int sidx;

    int n = blockIdx.x;
    int tid = threadIdx.x;
    float* ohrow = oh + (size_t)n * NEMB;

    if (tid < 64) kl[tid] = ((const u64*)ohrow)[tid];
    __syncthreads();
    if (tid == 0) {
        u64 best = ~0ull;
        for (int s = 0; s < 64; ++s)
            if (kl[s] < best) best = kl[s];
        sidx = (int)(best & 0xffffffffu);
    }
    __syncthreads();
    int idx = sidx;

    // zero the full one_hot row (8192 f32) — also erases the key stash
    float4 z4 = make_float4(0.f, 0.f, 0.f, 0.f);
    #pragma unroll
    for (int it = 0; it < 8; ++it)
        *(float4*)&ohrow[(it * 256 + tid) * 4] = z4;
    __syncthreads();

    zq[(size_t)n * 256 + tid] = E[(size_t)idx * 256 + tid];
    if (tid == 0) {
        idxf[n] = (float)idx;
        ohrow[idx] = 1.0f;
    }
}

// ---------------------------------------------------------------------------
extern "C" void kernel_launch(void* const* d_in, const int* in_sizes, int n_in,
                              void* d_out, int out_size, void* d_ws, size_t ws_size,
                              hipStream_t stream) {
    const float* ze  = (const float*)d_in[0];   // [16,256,32,32]
    const float* emb = (const float*)d_in[1];   // [8192,256]
    float* out = (float*)d_out;
    float* z    = out + Z_OFF;
    float* zq   = out + ZQ_OFF;
    float* idxf = out + IDX_OFF;
    float* oh   = out + OH_OFF;
    float* es   = (float*)((char*)d_ws + ES_OFF_BYTES);
    float* zs   = (float*)((char*)d_ws + ZS_OFF_BYTES);

    k_transpose<<<dim3(4, 16, 16), 256, 0, stream>>>(ze, z);
    k_rowsq<<<NEMB / 256, 256, 0, stream>>>(emb, es, NEMB);
    k_rowsq<<<NROWS / 256, 256, 0, stream>>>(z, zs, NROWS);
    k_dist<<<dim3(NEMB / BN, NROWS / BM), 256, 0, stream>>>(z, emb, es, zs, oh);
    k_final<<<NROWS, 256, 0, stream>>>(emb, zq, idxf, oh);
}

// Round 3
// 1263.694 us; speedup vs baseline: 1.4138x; 1.4138x over previous
//
#include <hip/hip_runtime.h>
#include <stdint.h>

typedef unsigned long long u64;

// Problem constants
#define NROWS 16384   // B*H*W = 16*32*32
#define CDIM  256
#define NEMB  8192

// d_out layout (float offsets): z | z_q | indices | one_hot
#define Z_OFF   0ull
#define ZQ_OFF  4194304ull
#define IDX_OFF 8388608ull
#define OH_OFF  8404992ull

// ws layout: es[8192] @0, zs[16384] @32KB, keys[16384*64 u64] @128KB (8MB)
#define ES_OFF_BYTES   0
#define ZS_OFF_BYTES   32768
#define KEYS_OFF_BYTES 131072

// order-preserving f32 -> u32 map (monotone increasing)
__device__ __forceinline__ unsigned fmap(float x) {
    unsigned u = __float_as_uint(x);
    return (u & 0x80000000u) ? ~u : (u | 0x80000000u);
}

// ---------------------------------------------------------------------------
// Kernel A: transpose z_e [B,C,H,W] -> z [B,H,W,C] (output 0; also GEMM A)
// ---------------------------------------------------------------------------
__global__ __launch_bounds__(256) void k_transpose(const float* __restrict__ ze,
                                                   float* __restrict__ z) {
    __shared__ float T[64][65];
    int b = blockIdx.z;          // 0..15
    int ct = blockIdx.x;         // 0..3   (c tiles of 64)
    int ht = blockIdx.y;         // 0..15  (hw tiles of 64)
    int c0 = ct * 64, hw0 = ht * 64;
    int lane = threadIdx.x & 63;
    int grp  = threadIdx.x >> 6; // 0..3
    #pragma unroll
    for (int i = 0; i < 16; ++i) {
        int cl = grp + i * 4;
        T[cl][lane] = ze[((size_t)(b * 256 + c0 + cl)) * 1024 + hw0 + lane];
    }
    __syncthreads();
    #pragma unroll
    for (int i = 0; i < 16; ++i) {
        int hwl = grp + i * 4;
        z[((size_t)(b * 1024 + hw0 + hwl)) * 256 + c0 + lane] = T[lane][hwl];
    }
}

// ---------------------------------------------------------------------------
// numpy pairwise_sum emulation (bit-exact), n=256 = pw128 + pw128.
// 8 accumulators, r[j] += fl(x[i+j]^2), combine ((r0+r1)+(r2+r3))+((r4+r5)+(r6+r7)).
// __f*_rn intrinsics forbid FMA contraction.
// ---------------------------------------------------------------------------
__device__ __forceinline__ float pw128sq(const float* __restrict__ x) {
    float r[8];
    #pragma unroll
    for (int j = 0; j < 8; ++j) r[j] = __fmul_rn(x[j], x[j]);
    #pragma unroll
    for (int i = 8; i < 128; i += 8) {
        #pragma unroll
        for (int j = 0; j < 8; ++j)
            r[j] = __fadd_rn(r[j], __fmul_rn(x[i + j], x[i + j]));
    }
    return __fadd_rn(__fadd_rn(__fadd_rn(r[0], r[1]), __fadd_rn(r[2], r[3])),
                     __fadd_rn(__fadd_rn(r[4], r[5]), __fadd_rn(r[6], r[7])));
}

// es[k] from embedding rows (one thread per row; L1/L2 absorb the stride)
__global__ __launch_bounds__(256) void k_rowsq(const float* __restrict__ X,
                                               float* __restrict__ out,
                                               int nrows) {
    int r = blockIdx.x * 256 + threadIdx.x;
    if (r >= nrows) return;
    const float* x = &X[(size_t)r * 256];
    out[r] = __fadd_rn(pw128sq(x), pw128sq(x + 128));
}

// zs directly from ze [B,C,H,W]: row (b,hw) = ze[b, c, hw], c ascending.
// Same pairwise order as pw128sq; coalesced across hw.
__global__ __launch_bounds__(256) void k_zsq(const float* __restrict__ ze,
                                             float* __restrict__ zs) {
    int t = blockIdx.x * 256 + threadIdx.x;   // 0..16383
    int b = t >> 10, hw = t & 1023;
    const float* base = ze + ((size_t)b * 256) * 1024 + hw;
    float half[2];
    #pragma unroll
    for (int hB = 0; hB < 2; ++hB) {
        const float* p = base + (size_t)(hB * 128) * 1024;
        float r[8];
        #pragma unroll
        for (int j = 0; j < 8; ++j) {
            float v = p[(size_t)j * 1024];
            r[j] = __fmul_rn(v, v);
        }
        #pragma unroll
        for (int i = 8; i < 128; i += 8) {
            #pragma unroll
            for (int j = 0; j < 8; ++j) {
                float v = p[(size_t)(i + j) * 1024];
                r[j] = __fadd_rn(r[j], __fmul_rn(v, v));
            }
        }
        half[hB] = __fadd_rn(__fadd_rn(__fadd_rn(r[0], r[1]), __fadd_rn(r[2], r[3])),
                             __fadd_rn(__fadd_rn(r[4], r[5]), __fadd_rn(r[6], r[7])));
    }
    zs[t] = __fadd_rn(half[0], half[1]);
}

// ---------------------------------------------------------------------------
// Kernel C: distance GEMM (f32 VALU, sequential-k FMA chain — bit-identical to
// round 2), conflict-free ds_read_b128 fragments, fused one-hot zero fill,
// per-(row, 128-col chunk) min-key -> ws keys.
// ---------------------------------------------------------------------------
#define BM 128
#define BN 128
#define BK 32
#define LDA 132   // 16B-aligned rows; +4 pad breaks power-of-2 stride

__global__ __launch_bounds__(256) void k_dist(const float* __restrict__ Z,
                                              const float* __restrict__ E,
                                              const float* __restrict__ es,
                                              const float* __restrict__ zs,
                                              float* __restrict__ oh,
                                              u64* __restrict__ keys) {
    __shared__ __align__(16) char smem[33792];  // As/Bs (33792B) ∪ red[128][17] u64
    float* As = (float*)smem;
    float* Bs = As + BK * LDA;
    u64*   red = (u64*)smem;

    int bx = blockIdx.x;   // col tile 0..63
    int by = blockIdx.y;   // row tile 0..127
    int tid = threadIdx.x;
    int tx = tid & 15, ty = tid >> 4;
    int row0 = by * BM, col0 = bx * BN;

    float acc[8][8] = {};   // row i: ty*4+(i&3)+(i>>2)*64 ; col j: tx*4+(j&3)+(j>>2)*64

    for (int kk = 0; kk < CDIM; kk += BK) {
        #pragma unroll
        for (int it = 0; it < 4; ++it) {
            int f4 = tid + it * 256;   // 0..1023
            int r = f4 >> 3, q = f4 & 7;
            float4 va = *(const float4*)&Z[((size_t)(row0 + r)) * CDIM + kk + q * 4];
            As[(q * 4 + 0) * LDA + r] = va.x;
            As[(q * 4 + 1) * LDA + r] = va.y;
            As[(q * 4 + 2) * LDA + r] = va.z;
            As[(q * 4 + 3) * LDA + r] = va.w;
            float4 vb = *(const float4*)&E[((size_t)(col0 + r)) * CDIM + kk + q * 4];
            Bs[(q * 4 + 0) * LDA + r] = vb.x;
            Bs[(q * 4 + 1) * LDA + r] = vb.y;
            Bs[(q * 4 + 2) * LDA + r] = vb.z;
            Bs[(q * 4 + 3) * LDA + r] = vb.w;
        }
        __syncthreads();
        for (int k = 0; k < BK; ++k) {
            float4 a0 = *(const float4*)&As[k * LDA + ty * 4];
            float4 a1 = *(const float4*)&As[k * LDA + 64 + ty * 4];
            float4 b0 = *(const float4*)&Bs[k * LDA + tx * 4];
            float4 b1 = *(const float4*)&Bs[k * LDA + 64 + tx * 4];
            float a[8] = {a0.x, a0.y, a0.z, a0.w, a1.x, a1.y, a1.z, a1.w};
            float b[8] = {b0.x, b0.y, b0.z, b0.w, b1.x, b1.y, b1.z, b1.w};
            #pragma unroll
            for (int i = 0; i < 8; ++i)
                #pragma unroll
                for (int j = 0; j < 8; ++j)
                    acc[i][j] = fmaf(a[i], b[j], acc[i][j]);
        }
        __syncthreads();
    }

    // epilogue: d = fl(fl(zs+es) - fl(2*dot))  (same ops/order as round 2)
    float esj[8], zsi[8];
    #pragma unroll
    for (int j = 0; j < 8; ++j) esj[j] = es[col0 + tx * 4 + (j & 3) + (j >> 2) * 64];
    #pragma unroll
    for (int i = 0; i < 8; ++i) zsi[i] = zs[row0 + ty * 4 + (i & 3) + (i >> 2) * 64];

    #pragma unroll
    for (int i = 0; i < 8; ++i) {
        int r = ty * 4 + (i & 3) + (i >> 2) * 64;
        u64 best = ~0ull;
        #pragma unroll
        for (int j = 0; j < 8; ++j) {
            int c = col0 + tx * 4 + (j & 3) + (j >> 2) * 64;
            float t1 = __fadd_rn(zsi[i], esj[j]);
            float t2 = __fmul_rn(2.0f, acc[i][j]);
            float d  = __fsub_rn(t1, t2);
            u64 key = ((u64)fmap(d) << 32) | (unsigned)c;
            if (key < best) best = key;
        }
        red[r * 17 + tx] = best;
    }
    __syncthreads();
    if (tid < 128) {
        u64 best = ~0ull;
        #pragma unroll
        for (int s = 0; s < 16; ++s) {
            u64 k = red[tid * 17 + s];
            if (k < best) best = k;
        }
        keys[((size_t)(row0 + tid)) * 64 + bx] = best;
    }

    // fused one-hot zero fill for this 128x128 tile
    float4 z4 = make_float4(0.f, 0.f, 0.f, 0.f);
    #pragma unroll
    for (int it = 0; it < 16; ++it) {
        int f4 = tid + it * 256;       // 0..4095
        int r = f4 >> 5, q = f4 & 31;
        *(float4*)&oh[((size_t)(row0 + r)) * NEMB + col0 + q * 4] = z4;
    }
}

// ---------------------------------------------------------------------------
// Kernel D: per-row finalize — one wave per row: min over 64 chunk keys
// (np first-min tie-break), write index / z_q / the single 1.0.
// ---------------------------------------------------------------------------
__global__ __launch_bounds__(256) void k_final(const float* __restrict__ E,
                                               const u64* __restrict__ keys,
                                               float* __restrict__ zq,
                                               float* __restrict__ idxf,
                                               float* __restrict__ oh) {
    int wave = threadIdx.x >> 6, lane = threadIdx.x & 63;
    int n = blockIdx.x * 4 + wave;
    u64 k = keys[(size_t)n * 64 + lane];
    #pragma unroll
    for (int off = 32; off > 0; off >>= 1) {
        u64 o = __shfl_down(k, off);
        if (o < k) k = o;
    }
    k = __shfl(k, 0);
    int idx = (int)(k & 0xffffffffu);
    float4 e4 = *(const float4*)&E[(size_t)idx * 256 + lane * 4];
    *(float4*)&zq[(size_t)n * 256 + lane * 4] = e4;
    if (lane == 0) {
        idxf[n] = (float)idx;
        oh[(size_t)n * NEMB + idx] = 1.0f;
    }
}

// ---------------------------------------------------------------------------
extern "C" void kernel_launch(void* const* d_in, const int* in_sizes, int n_in,
                              void* d_out, int out_size, void* d_ws, size_t ws_size,
                              hipStream_t stream) {
    const float* ze  = (const float*)d_in[0];   // [16,256,32,32]
    const float* emb = (const float*)d_in[1];   // [8192,256]
    float* out = (float*)d_out;
    float* z    = out + Z_OFF;
    float* zq   = out + ZQ_OFF;
    float* idxf = out + IDX_OFF;
    float* oh   = out + OH_OFF;
    float* es   = (float*)((char*)d_ws + ES_OFF_BYTES);
    float* zs   = (float*)((char*)d_ws + ZS_OFF_BYTES);
    u64*   keys = (u64*)((char*)d_ws + KEYS_OFF_BYTES);

    k_transpose<<<dim3(4, 16, 16), 256, 0, stream>>>(ze, z);
    k_zsq<<<NROWS / 256, 256, 0, stream>>>(ze, zs);
    k_rowsq<<<NEMB / 256, 256, 0, stream>>>(emb, es, NEMB);
    k_dist<<<dim3(NEMB / BN, NROWS / BM), 256, 0, stream>>>(z, emb, es, zs, oh, keys);
    k_final<<<NROWS / 4, 256, 0, stream>>>(emb, keys, zq, idxf, oh);
}